// Round 1
// baseline (360.821 us; speedup 1.0000x reference)
//
#include <hip/hip_runtime.h>

#define BATCH 8
#define DIM 192
#define HH 128
#define WW 128
#define KS 7
#define PAD 3
#define HID 48
#define KK 49            // KS*KS
#define BN_EPS 1e-5f

#define TILE_H 32
#define SROWS (TILE_H + KS - 1)   // 38
#define SW 136                    // 4 left halo + 128 + 4 right halo (float4-aligned)

// ---------------- Kernel A: global average pool over H*W ----------------
__global__ __launch_bounds__(256) void pool_kernel(const float* __restrict__ x,
                                                   float* __restrict__ pooled) {
    const int bc = blockIdx.x;                       // 0..B*DIM-1
    const float4* p = (const float4*)(x + (size_t)bc * HH * WW);
    const int t = threadIdx.x;
    float s = 0.f;
#pragma unroll
    for (int i = 0; i < 16; ++i) {                   // 16384 floats = 4096 float4 / 256 thr
        float4 v = p[t + i * 256];
        s += (v.x + v.y) + (v.z + v.w);
    }
    // wave(64) shuffle reduce
#pragma unroll
    for (int off = 32; off > 0; off >>= 1) s += __shfl_down(s, off, 64);
    __shared__ float wsum[4];
    const int wave = t >> 6, lane = t & 63;
    if (lane == 0) wsum[wave] = s;
    __syncthreads();
    if (t == 0) {
        float tot = (wsum[0] + wsum[1]) + (wsum[2] + wsum[3]);
        pooled[bc] = tot * (1.0f / (HH * WW));
    }
}

// ---------------- Kernel B: weight generation (per batch) ----------------
__global__ __launch_bounds__(256) void wgen_kernel(const float* __restrict__ pooled,
                                                   const float* __restrict__ w1,
                                                   const float* __restrict__ gamma,
                                                   const float* __restrict__ beta,
                                                   const float* __restrict__ mean,
                                                   const float* __restrict__ var,
                                                   const float* __restrict__ w2,
                                                   const float* __restrict__ b2,
                                                   float* __restrict__ wdyn) {
    const int b = blockIdx.x;
    __shared__ float pool_s[DIM];
    __shared__ float y_s[HID];
    const int t = threadIdx.x;
    if (t < DIM) pool_s[t] = pooled[b * DIM + t];
    __syncthreads();
    if (t < HID) {
        float acc = 0.f;
#pragma unroll 4
        for (int c = 0; c < DIM; ++c) acc += pool_s[c] * w1[t * DIM + c];
        float yv = (acc - mean[t]) * rsqrtf(var[t] + BN_EPS) * gamma[t] + beta[t];
        y_s[t] = yv > 0.f ? yv : 0.f;
    }
    __syncthreads();
    for (int o = t; o < DIM * KK; o += 256) {
        const float4* w2r = (const float4*)(w2 + (size_t)o * HID);
        float acc = b2[o];
#pragma unroll
        for (int j = 0; j < HID / 4; ++j) {
            float4 wv = w2r[j];
            acc += y_s[4 * j] * wv.x + y_s[4 * j + 1] * wv.y +
                   y_s[4 * j + 2] * wv.z + y_s[4 * j + 3] * wv.w;
        }
        wdyn[(size_t)b * DIM * KK + o] = acc;
    }
}

// ---------------- Kernel C: depthwise 7x7 conv with dynamic weights ----------------
__global__ __launch_bounds__(256) void dwconv_kernel(const float* __restrict__ x,
                                                     const float* __restrict__ wdyn,
                                                     const float* __restrict__ bias,
                                                     float* __restrict__ out) {
    __shared__ float smem[SROWS][SW];
    __shared__ float wk_s[KK];
    const int tile = blockIdx.x & 3;
    const int bc = blockIdx.x >> 2;                  // b*DIM + c
    const int c = bc % DIM;
    const int t = threadIdx.x;
    const int r0 = tile * TILE_H;

    if (t < KK) wk_s[t] = wdyn[(size_t)bc * KK + t];

    // stage input rows r0-3 .. r0+34 (zero outside), cols 0..127 -> smem idx 4..131
    const float* xp = x + (size_t)bc * HH * WW;
    for (int idx = t; idx < SROWS * 32; idx += 256) {
        const int r = idx >> 5;                      // 0..37
        const int c4 = idx & 31;                     // float4 index in row
        const int gr = r0 - PAD + r;
        float4 v = make_float4(0.f, 0.f, 0.f, 0.f);
        if (gr >= 0 && gr < HH) v = ((const float4*)(xp + (size_t)gr * WW))[c4];
        *((float4*)&smem[r][4 + c4 * 4]) = v;
    }
    // zero halo columns (cols -4..-1 and 128..131)
    if (t < SROWS * 2) {
        const int r = t >> 1;
        float4* p = (float4*)&smem[r][(t & 1) ? 132 : 0];
        *p = make_float4(0.f, 0.f, 0.f, 0.f);
    }
    __syncthreads();

    float wreg[KK];
#pragma unroll
    for (int i = 0; i < KK; ++i) wreg[i] = wk_s[i];
    const float bv = bias[c];

    const int lr = t >> 5;                           // 0..7: row within pass
    const int c4 = t & 31;                           // col group (4 cols)
    float* outp = out + (size_t)bc * HH * WW;

#pragma unroll
    for (int pass = 0; pass < 4; ++pass) {
        const int row = pass * 8 + lr;               // output row in tile, 0..31
        float a0 = 0.f, a1 = 0.f, a2 = 0.f, a3 = 0.f;
#pragma unroll
        for (int ky = 0; ky < KS; ++ky) {
            const float* srow = &smem[row + ky][0];
            const float4 f0 = ((const float4*)srow)[c4];
            const float4 f1 = ((const float4*)srow)[c4 + 1];
            const float4 f2 = ((const float4*)srow)[c4 + 2];
            const float v[12] = {f0.x, f0.y, f0.z, f0.w,
                                 f1.x, f1.y, f1.z, f1.w,
                                 f2.x, f2.y, f2.z, f2.w};
#pragma unroll
            for (int kx = 0; kx < KS; ++kx) {
                const float wv = wreg[ky * KS + kx];
                a0 += wv * v[1 + kx];
                a1 += wv * v[2 + kx];
                a2 += wv * v[3 + kx];
                a3 += wv * v[4 + kx];
            }
        }
        float4 o4 = make_float4(a0 + bv, a1 + bv, a2 + bv, a3 + bv);
        ((float4*)(outp + (size_t)(r0 + row) * WW))[c4] = o4;
    }
}

extern "C" void kernel_launch(void* const* d_in, const int* in_sizes, int n_in,
                              void* d_out, int out_size, void* d_ws, size_t ws_size,
                              hipStream_t stream) {
    const float* x     = (const float*)d_in[0];
    const float* w1    = (const float*)d_in[1];
    const float* gamma = (const float*)d_in[2];
    const float* beta  = (const float*)d_in[3];
    const float* mean  = (const float*)d_in[4];
    const float* var   = (const float*)d_in[5];
    const float* w2    = (const float*)d_in[6];
    const float* b2    = (const float*)d_in[7];
    const float* bias  = (const float*)d_in[8];
    float* out = (float*)d_out;

    float* pooled = (float*)d_ws;                        // B*DIM floats
    float* wdyn   = pooled + BATCH * DIM;                // B*DIM*KK floats

    pool_kernel<<<BATCH * DIM, 256, 0, stream>>>(x, pooled);
    wgen_kernel<<<BATCH, 256, 0, stream>>>(pooled, w1, gamma, beta, mean, var,
                                           w2, b2, wdyn);
    dwconv_kernel<<<BATCH * DIM * 4, 256, 0, stream>>>(x, wdyn, bias, out);
}

// Round 3
// 237.331 us; speedup vs baseline: 1.5203x; 1.5203x over previous
//
#include <hip/hip_runtime.h>

#define BATCH 8
#define DIM 192
#define HH 128
#define WW 128
#define KS 7
#define PAD 3
#define HID 48
#define KK 49            // KS*KS
#define BN_EPS 1e-5f

#define TILE_H 64
#define SROWS (TILE_H + KS - 1)   // 70
#define SW 136                    // 4 left halo + 128 + 4 right halo (float4-aligned)

// ---------------- Kernel A: global average pool over H*W ----------------
__global__ __launch_bounds__(256) void pool_kernel(const float* __restrict__ x,
                                                   float* __restrict__ pooled) {
    const int bc = blockIdx.x;                       // 0..B*DIM-1
    const float4* p = (const float4*)(x + (size_t)bc * HH * WW);
    const int t = threadIdx.x;
    float s = 0.f;
#pragma unroll
    for (int i = 0; i < 16; ++i) {                   // 16384 floats = 4096 float4 / 256 thr
        float4 v = p[t + i * 256];
        s += (v.x + v.y) + (v.z + v.w);
    }
#pragma unroll
    for (int off = 32; off > 0; off >>= 1) s += __shfl_down(s, off, 64);
    __shared__ float wsum[4];
    const int wave = t >> 6, lane = t & 63;
    if (lane == 0) wsum[wave] = s;
    __syncthreads();
    if (t == 0) {
        float tot = (wsum[0] + wsum[1]) + (wsum[2] + wsum[3]);
        pooled[bc] = tot * (1.0f / (HH * WW));
    }
}

// ---------------- Kernel B1: y = relu(BN(pooled @ w1^T))  [B*HID outputs] ----
__global__ __launch_bounds__(384) void wgen_y_kernel(const float* __restrict__ pooled,
                                                     const float* __restrict__ w1,
                                                     const float* __restrict__ gamma,
                                                     const float* __restrict__ beta,
                                                     const float* __restrict__ mean,
                                                     const float* __restrict__ var,
                                                     float* __restrict__ y) {
    const int t = threadIdx.x;                       // 0..383
    const int b = t / HID, h = t % HID;
    const float4* pr = (const float4*)(pooled + b * DIM);
    const float4* wr = (const float4*)(w1 + (size_t)h * DIM);
    float acc = 0.f;
#pragma unroll
    for (int j = 0; j < DIM / 4; ++j) {
        float4 pv = pr[j], wv = wr[j];
        acc += pv.x * wv.x + pv.y * wv.y + pv.z * wv.z + pv.w * wv.w;
    }
    float yv = (acc - mean[h]) * rsqrtf(var[h] + BN_EPS) * gamma[h] + beta[h];
    y[t] = yv > 0.f ? yv : 0.f;
}

// ---------------- Kernel B2: wdyn = y @ w2^T + b2  [B*DIM*KK outputs] --------
__global__ __launch_bounds__(256) void wgen_w2_kernel(const float* __restrict__ y,
                                                      const float* __restrict__ w2,
                                                      const float* __restrict__ b2,
                                                      float* __restrict__ wdyn) {
    __shared__ float y_s[BATCH * HID];               // 384 floats
    const int t = threadIdx.x;
    for (int i = t; i < BATCH * HID; i += 256) y_s[i] = y[i];  // FIX: grid-stride (384 > 256)
    __syncthreads();
    const int o = blockIdx.x * 256 + t;              // < B*DIM*KK = 75264
    const int b = o / (DIM * KK);
    const int ol = o - b * (DIM * KK);
    const float4* w2r = (const float4*)(w2 + (size_t)ol * HID);
    const float* yb = y_s + b * HID;
    float acc = b2[ol];
#pragma unroll
    for (int j = 0; j < HID / 4; ++j) {
        float4 wv = w2r[j];
        acc += yb[4 * j] * wv.x + yb[4 * j + 1] * wv.y +
               yb[4 * j + 2] * wv.z + yb[4 * j + 3] * wv.w;
    }
    wdyn[o] = acc;
}

// ---------------- Kernel C: depthwise 7x7 conv, sliding-window ring ----------
// Thread map: c4 = t&31 (4-col group), strip = t>>5 (8 strips x 8 rows).
// Half-waves are 8 rows apart: 8*136 floats == 0 mod 32 banks -> same bank
// phase (2-way aliasing only, free per m136). Each thread slides over 14 input
// rows, 3 ds_read_b128 per row, feeding a 7-deep ring of 4-wide accumulators.
__global__ __launch_bounds__(256) void dwconv_kernel(const float* __restrict__ x,
                                                     const float* __restrict__ wdyn,
                                                     const float* __restrict__ bias,
                                                     float* __restrict__ out) {
    __shared__ float smem[SROWS][SW];                // 70*136*4 = 38080 B
    __shared__ float wk_s[KK];
    const int tile = blockIdx.x & 1;                 // 2 tiles of 64 rows
    const int bc = blockIdx.x >> 1;                  // b*DIM + c
    const int c = bc % DIM;
    const int t = threadIdx.x;
    const int r0 = tile * TILE_H;

    if (t < KK) wk_s[t] = wdyn[(size_t)bc * KK + t];

    // stage rows r0-3 .. r0+66 (zero outside), cols 0..127 -> smem cols 4..131
    const float* xp = x + (size_t)bc * HH * WW;
    for (int idx = t; idx < SROWS * 32; idx += 256) {
        const int r = idx >> 5;
        const int c4 = idx & 31;
        const int gr = r0 - PAD + r;
        float4 v = make_float4(0.f, 0.f, 0.f, 0.f);
        if (gr >= 0 && gr < HH) v = ((const float4*)(xp + (size_t)gr * WW))[c4];
        *((float4*)&smem[r][4 + c4 * 4]) = v;
    }
    if (t < SROWS * 2) {                             // zero halo cols
        const int r = t >> 1;
        float4* p = (float4*)&smem[r][(t & 1) ? 132 : 0];
        *p = make_float4(0.f, 0.f, 0.f, 0.f);
    }
    __syncthreads();

    float wreg[KK];
#pragma unroll
    for (int i = 0; i < KK; ++i) wreg[i] = wk_s[i];
    const float bv = bias[c];

    const int c4 = t & 31;
    const int strip = t >> 5;                        // 0..7
    const int sbase = strip * 8;                     // first smem row of window
    float* outp = out + (size_t)bc * HH * WW + (size_t)(r0 + sbase) * WW + c4 * 4;

    float acc[7][4];
#pragma unroll
    for (int i = 0; i < 7; ++i)
        acc[i][0] = acc[i][1] = acc[i][2] = acc[i][3] = 0.f;

#pragma unroll
    for (int ir = 0; ir < TILE_H / 8 + KS - 1; ++ir) {   // 14 input rows
        const float* srow = &smem[sbase + ir][0];
        const float4 f0 = ((const float4*)srow)[c4];
        const float4 f1 = ((const float4*)srow)[c4 + 1];
        const float4 f2 = ((const float4*)srow)[c4 + 2];
        const float v[12] = {f0.x, f0.y, f0.z, f0.w,
                             f1.x, f1.y, f1.z, f1.w,
                             f2.x, f2.y, f2.z, f2.w};
#pragma unroll
        for (int ky = 0; ky < KS; ++ky) {
            const int o = ir - ky;                   // pending output row
            if (o >= 0 && o < 8) {
                float* a = acc[o % 7];
#pragma unroll
                for (int kx = 0; kx < KS; ++kx) {
                    const float wv = wreg[ky * KS + kx];
                    a[0] += wv * v[1 + kx];
                    a[1] += wv * v[2 + kx];
                    a[2] += wv * v[3 + kx];
                    a[3] += wv * v[4 + kx];
                }
            }
        }
        if (ir >= 6) {                               // output row ir-6 complete
            float* a = acc[(ir - 6) % 7];
            float4 o4 = make_float4(a[0] + bv, a[1] + bv, a[2] + bv, a[3] + bv);
            *((float4*)(outp + (size_t)(ir - 6) * WW)) = o4;
            a[0] = a[1] = a[2] = a[3] = 0.f;
        }
    }
}

extern "C" void kernel_launch(void* const* d_in, const int* in_sizes, int n_in,
                              void* d_out, int out_size, void* d_ws, size_t ws_size,
                              hipStream_t stream) {
    const float* x     = (const float*)d_in[0];
    const float* w1    = (const float*)d_in[1];
    const float* gamma = (const float*)d_in[2];
    const float* beta  = (const float*)d_in[3];
    const float* mean  = (const float*)d_in[4];
    const float* var   = (const float*)d_in[5];
    const float* w2    = (const float*)d_in[6];
    const float* b2    = (const float*)d_in[7];
    const float* bias  = (const float*)d_in[8];
    float* out = (float*)d_out;

    float* pooled = (float*)d_ws;                    // B*DIM
    float* y      = pooled + BATCH * DIM;            // B*HID
    float* wdyn   = y + BATCH * HID;                 // B*DIM*KK

    pool_kernel<<<BATCH * DIM, 256, 0, stream>>>(x, pooled);
    wgen_y_kernel<<<1, 384, 0, stream>>>(pooled, w1, gamma, beta, mean, var, y);
    wgen_w2_kernel<<<(BATCH * DIM * KK) / 256, 256, 0, stream>>>(y, w2, b2, wdyn);
    dwconv_kernel<<<BATCH * DIM * 2, 256, 0, stream>>>(x, wdyn, bias, out);
}